// Round 18
// baseline (7484.538 us; speedup 1.0000x reference)
//
#include <hip/hip_runtime.h>
#include <stdint.h>

// ---------------------------------------------------------------------------
// R25 = R24 (7.36ms, best) + LAST-ARRIVER-BROADCAST barrier.
//   R24 analysis: compute ~0.7-1.5us/phase vs phase 8.5us -> barrier is
//   75-85% of runtime. Largest soft term: the leader's detect poll (after the
//   last arrival RMW lands, the leader must NOTICE it: one system-load RTT +
//   up-to-one poll iteration ~1-1.5us). But fetch_add RETURNS the old value:
//   the last arriver KNOWS it is last for free.
//   New barrier: arrival old=fetch_add(line,1); if old==gen*16-1 (line full)
//   -> old2=fetch_add(summary,1); if old2==gen*4-1 (all 4 lines full) ->
//   system-store go=gen. No leader, no detect poll; detection latency =
//   RMW-response time. Pollers unchanged (system-load go, s_sleep(1), abort
//   guard, acquire-inv exit). Ordering: h system-stores drained (vmcnt0 in
//   syncthreads) before arrival RMW; go observed => summary done => all 64
//   arrivals done => all h data at the coherence point; inv => fresh reads.
//   Everything else byte-identical to R24: 256 blk x 256 thr (full GPU,
//   4 supergroups x 64 roles), decoder both-role split-acc, system-scope
//   packed h stores, plain b128 L2-shared h reads, LDS-resident frag
//   weights, Wy rank-1 y-feedback, emitY, abort guard, plain launch.
// ---------------------------------------------------------------------------

typedef __attribute__((ext_vector_type(8))) short bfx8;   // 8 bf16 (4 VGPRs)
typedef __attribute__((ext_vector_type(4))) float fx4;

#define NBLK 256
#define NTHR 256
#define BH   (256*512)

__device__ __forceinline__ unsigned short f2bf(float f){
  unsigned u = __float_as_uint(f);
  u += 0x7FFFu + ((u >> 16) & 1u);          // RNE
  return (unsigned short)(u >> 16);
}
__device__ __forceinline__ float bf2f(unsigned short b){
  return __uint_as_float(((unsigned)b) << 16);
}
__device__ __forceinline__ float sigm(float x){ return 1.0f/(1.0f + __expf(-x)); }
__device__ __forceinline__ float tanhf_(float x){
  x = fminf(12.0f, fmaxf(-12.0f, x));
  float e = __expf(2.0f*x);
  return (e - 1.0f)/(e + 1.0f);
}

// 64-block supergroup barrier, last-arriver-broadcast.
//   arrival: old = relaxed agent fetch_add on this block's sub-counter line.
//   line-completer (old==gen*16-1): bumps summary; summary-completer
//   (old==gen*4-1): system-stores go=gen (then proceeds directly).
//   everyone else: polls go with system loads (RTT-dominated; s_sleep(1)).
//   exit: acquire load -> buffer_inv so plain h loads refill fresh.
__device__ __forceinline__ bool groupbar(unsigned* cntg, int sub, unsigned gen,
                                         unsigned* summary, unsigned* go,
                                         unsigned* abortf, volatile unsigned* s_abort){
  __syncthreads();
  if (threadIdx.x == 0){
    unsigned old = __hip_atomic_fetch_add(cntg + sub*32, 1u, __ATOMIC_RELAXED, __HIP_MEMORY_SCOPE_AGENT);
    bool done = false;
    if (old == gen*16u - 1u){                    // my line just completed
      unsigned old2 = __hip_atomic_fetch_add(summary, 1u, __ATOMIC_RELAXED, __HIP_MEMORY_SCOPE_AGENT);
      if (old2 == gen*4u - 1u){                  // all 4 lines complete
        __hip_atomic_store(go, gen, __ATOMIC_RELAXED, __HIP_MEMORY_SCOPE_SYSTEM);
        done = true;                             // broadcaster proceeds now
      }
    }
    if (!done){
      unsigned spins = 0;
      while (__hip_atomic_load(go, __ATOMIC_RELAXED, __HIP_MEMORY_SCOPE_SYSTEM) < gen){
        if (((++spins) & 1023u) == 0u){
          if (__hip_atomic_load(abortf, __ATOMIC_RELAXED, __HIP_MEMORY_SCOPE_AGENT) != 0u){
            *s_abort = 1u; break;
          }
          if (spins > (1u << 20)){
            __hip_atomic_store(abortf, 1u, __ATOMIC_RELAXED, __HIP_MEMORY_SCOPE_AGENT);
            *s_abort = 1u; break;
          }
        }
        __builtin_amdgcn_s_sleep(1);
      }
    }
    (void)__hip_atomic_load(cntg, __ATOMIC_ACQUIRE, __HIP_MEMORY_SCOPE_AGENT);  // buffer_inv
  }
  __syncthreads();
  return *s_abort != 0u;
}

// K=512 accumulate: A rows from global h via PLAIN b128 loads (L2-cached,
// fresh after the barrier's inv); B = 4 gate-slices from LDS fragment layout.
__device__ __forceinline__ void accK512_lds(fx4* acc, const uint16_t* aq,
                                            const uint16_t* wl, int lane8){
  #pragma unroll
  for (int kc = 0; kc < 16; ++kc){
    bfx8 af = *(const bfx8*)(aq + kc*32);
    acc[0] = __builtin_amdgcn_mfma_f32_16x16x32_bf16(af, *(const bfx8*)(wl +         kc*512 + lane8), acc[0], 0, 0, 0);
    acc[1] = __builtin_amdgcn_mfma_f32_16x16x32_bf16(af, *(const bfx8*)(wl +  8192 + kc*512 + lane8), acc[1], 0, 0, 0);
    acc[2] = __builtin_amdgcn_mfma_f32_16x16x32_bf16(af, *(const bfx8*)(wl + 16384 + kc*512 + lane8), acc[2], 0, 0, 0);
    acc[3] = __builtin_amdgcn_mfma_f32_16x16x32_bf16(af, *(const bfx8*)(wl + 24576 + kc*512 + lane8), acc[3], 0, 0, 0);
  }
}

// LSTM pointwise; h store = packed 2-col SYSTEM-scope atomic dword.
__device__ __forceinline__ void pointwise(fx4* acc, fx4& creg, int bq, int u,
                                          int col, uint16_t* hout){
  #pragma unroll
  for (int r = 0; r < 4; ++r){
    float iv = sigm(acc[0][r]);
    float fv = sigm(acc[1][r]);
    float gv = tanhf_(acc[2][r]);
    float ov = sigm(acc[3][r]);
    float cn = fv * creg[r] + iv * gv;
    creg[r] = cn;
    unsigned hb = (unsigned)f2bf(ov * tanhf_(cn));
    unsigned nb = __shfl_xor(hb, 1);
    if ((col & 1) == 0){
      __hip_atomic_store((unsigned*)(hout + (size_t)(bq + r)*512 + u), hb | (nb << 16),
                         __ATOMIC_RELAXED, __HIP_MEMORY_SCOPE_SYSTEM);
    }
  }
}

__global__ void __launch_bounds__(NTHR)
seq2seq_main(const uint16_t* __restrict__ Whh0e, const uint16_t* __restrict__ Wih1e,
             const uint16_t* __restrict__ Whh1e, const uint16_t* __restrict__ Whh0d,
             const uint16_t* __restrict__ Wih1d, const uint16_t* __restrict__ Whh1d,
             const uint16_t* __restrict__ Wy,
             const float* __restrict__ E0e, const float* __restrict__ E0d,
             const float* __restrict__ b1e, const float* __restrict__ b1d,
             const float* __restrict__ wcol0,
             uint16_t* h0buf, uint16_t* h1buf,
             const float* __restrict__ xh, const float* __restrict__ xf,
             const float* __restrict__ y0v,
             const float* __restrict__ encWih0, const float* __restrict__ decWih0,
             const float* __restrict__ projW, const float* __restrict__ projB,
             float* out, unsigned* cntBase)
{
  __shared__ uint4 smem4[8192];                 // 128 KiB static LDS
  __shared__ unsigned s_abort;
  uint16_t* smem = (uint16_t*)smem4;

  const int tid  = threadIdx.x;
  const int lane = tid & 63;
  const int wvi  = tid >> 6;                    // wave in block, 0..3
  const int sg   = blockIdx.x >> 6;             // supergroup (64 batch rows), 0..3
  const int k    = blockIdx.x & 63;             // role: 0..31 L0, 32..63 L1
  const bool isL0 = (k < 32);
  const int role = isL0 ? k : k - 32;           // u-slice index, 0..31
  const int col  = lane & 15;
  const int quad = lane >> 4;
  const int rowbase = (sg << 6) + (wvi << 4);   // wave's 16-row M-tile base
  const int bq   = rowbase + (quad << 2);
  const int u    = (role << 4) + col;
  const int lane8 = lane << 3;
  unsigned* cntg    = cntBase + (size_t)sg * 128;  // 4 counters x 128B / sg
  unsigned* abortf  = cntBase + 512;               // abort flag (own line)
  unsigned* summary = cntBase + 544 + sg*32;       // summary line / sg
  unsigned* go      = cntBase + 672 + sg*32;       // go word / sg
  const int sub  = k >> 4;
  unsigned gen = 0;
  fx4 creg = {0.f, 0.f, 0.f, 0.f};              // c0 (L0) or c1 (L1)
  const float projB_val = projB[0];
  const int hoff = (rowbase + col)*512 + (quad << 3);

  if (tid == 0) s_abort = 0u;

  uint16_t *h0A = h0buf, *h0B = h0buf + BH;
  uint16_t *h1A = h1buf, *h1B = h1buf + BH;

  // ---- stage encoder weight slices into LDS ----
  if (isL0){
    const uint4* s0 = (const uint4*)(Whh0e + (size_t)role*32768);
    for (int i = tid; i < 4096; i += NTHR) smem4[i] = s0[i];
  } else {
    const uint4* s0 = (const uint4*)(Wih1e + (size_t)role*32768);
    const uint4* s1 = (const uint4*)(Whh1e + (size_t)role*32768);
    for (int i = tid; i < 4096; i += NTHR){ smem4[i] = s0[i]; smem4[4096+i] = s1[i]; }
  }

  // ---- hoist per-lane constants into registers ----
  float e0r[4][4], xw[4][8], wc[4], b1r[4], pw8[8];
  if (isL0){
    #pragma unroll
    for (int gg = 0; gg < 4; ++gg){
      #pragma unroll
      for (int r = 0; r < 4; ++r)
        e0r[gg][r] = E0e[(size_t)(bq + r)*2048 + (gg << 9) + u];
      #pragma unroll
      for (int kk = 0; kk < 8; ++kk)
        xw[gg][kk] = encWih0[(size_t)((gg << 9) + u)*24 + kk];
    }
  } else {
    #pragma unroll
    for (int gg = 0; gg < 4; ++gg) b1r[gg] = b1e[(gg << 9) + u];
    if (k < 36){                                // emitY blocks k=32..35
      #pragma unroll
      for (int kk = 0; kk < 8; ++kk) pw8[kk] = projW[lane8 + kk];
    }
  }
  __syncthreads();

  auto encCompute = [&](int tt, const uint16_t* h0c, uint16_t* h0n){
    fx4 acc[4];
    #pragma unroll
    for (int gg = 0; gg < 4; ++gg)
      #pragma unroll
      for (int r = 0; r < 4; ++r) acc[gg][r] = e0r[gg][r];
    float xv[4][8];
    #pragma unroll
    for (int r = 0; r < 4; ++r){
      const float* xr = xh + ((size_t)(bq + r)*288 + tt)*8;
      #pragma unroll
      for (int kk = 0; kk < 8; ++kk) xv[r][kk] = xr[kk];
    }
    accK512_lds(acc, h0c + hoff, smem, lane8);
    #pragma unroll
    for (int gg = 0; gg < 4; ++gg)
      #pragma unroll
      for (int kk = 0; kk < 8; ++kk){
        float w = xw[gg][kk];
        #pragma unroll
        for (int r = 0; r < 4; ++r) acc[gg][r] += w * xv[r][kk];
      }
    pointwise(acc, creg, bq, u, col, h0n);
  };

  // emitY: blocks k=32..35 cover the supergroup's 64 rows (16 each); wave wvi
  // covers 4 rows. Plain loads (fresh after barrier inv); single-writer out.
  auto emitY = [&](const uint16_t* h1cur, int tt){
    int rb = (sg << 6) + ((k - 32) << 4) + (wvi << 2);
    #pragma unroll 1
    for (int j = 0; j < 4; ++j){
      int b = rb + j;
      const uint16_t* hr = h1cur + (size_t)b*512 + lane8;
      float part = 0.f;
      #pragma unroll
      for (int kk = 0; kk < 8; ++kk) part += bf2f(hr[kk]) * pw8[kk];
      #pragma unroll
      for (int off = 32; off > 0; off >>= 1) part += __shfl_down(part, off);
      if (lane == 0) out[(size_t)b*288 + tt] = part + projB_val;
    }
  };

  // ---- prologue: enc L0 t=0 (h_{-1}=0 via memset) ----
  if (isL0) encCompute(0, h0A, h0B);
  if (groupbar(cntg, sub, ++gen, summary, go, abortf, &s_abort)) return;
  { uint16_t* t_ = h0A; h0A = h0B; h0B = t_; }   // h0A = h0_0

  // ---- encoder: 1 barrier/step; L1_t || L0_{t+1} ----
  #pragma unroll 1
  for (int t = 0; t < 288; ++t){
    if (isL0){
      if (t < 287) encCompute(t + 1, h0A, h0B);
    } else {
      fx4 acc[4];
      #pragma unroll
      for (int gg = 0; gg < 4; ++gg)
        #pragma unroll
        for (int r = 0; r < 4; ++r) acc[gg][r] = b1r[gg];
      accK512_lds(acc, h0A + hoff, smem, lane8);            // Wih1e * h0_t
      accK512_lds(acc, h1A + hoff, smem + 32768, lane8);    // Whh1e * h1_{t-1}
      pointwise(acc, creg, bq, u, col, h1B);
    }
    if (groupbar(cntg, sub, ++gen, summary, go, abortf, &s_abort)) return;
    { uint16_t* t_ = h1A; h1A = h1B; h1B = t_; }
    if (t < 287){ uint16_t* t_ = h0A; h0A = h0B; h0B = t_; }
  }
  // h0A = h0_287, h1A = h1_287; c continues into decoder.

  // ---- restage decoder weights + regs (block-local) ----
  if (isL0){
    const uint4* s0 = (const uint4*)(Whh0d + (size_t)role*32768);
    const uint4* s1 = (const uint4*)(Wy    + (size_t)role*32768);
    for (int i = tid; i < 4096; i += NTHR){ smem4[i] = s0[i]; smem4[4096+i] = s1[i]; }
    #pragma unroll
    for (int gg = 0; gg < 4; ++gg){
      #pragma unroll
      for (int r = 0; r < 4; ++r)
        e0r[gg][r] = E0d[(size_t)(bq + r)*2048 + (gg << 9) + u];
      #pragma unroll
      for (int kk = 0; kk < 6; ++kk)
        xw[gg][kk] = decWih0[(size_t)((gg << 9) + u)*23 + 1 + kk];
      wc[gg] = wcol0[(gg << 9) + u];
    }
  } else {
    const uint4* s0 = (const uint4*)(Wih1d + (size_t)role*32768);
    const uint4* s1 = (const uint4*)(Whh1d + (size_t)role*32768);
    for (int i = tid; i < 4096; i += NTHR){ smem4[i] = s0[i]; smem4[4096+i] = s1[i]; }
    #pragma unroll
    for (int gg = 0; gg < 4; ++gg) b1r[gg] = b1d[(gg << 9) + u];
  }
  __syncthreads();

  // ---- decoder: 2 barriers/step; BOTH roles' acc pairs split across phases.
  // Phase A (step t): L0 finishes accL0 += Wy*h1_{t-1} (+wc*s +x), pointwise
  //                   -> h0_t; L1 starts accL1 = b1 + Whh1d*h1_{t-1}, emitY.
  // Phase B (step t): L1 finishes accL1 += Wih1d*h0_t, pointwise -> h1_t;
  //                   L0 prefetches accL0 = E0d + Whh0d*h0_t for step t+1.
  // Accumulation order e0r -> Whh0d -> Wy -> wc*s -> x identical to R24.
  fx4 accL0[4], accL1[4];
  if (isL0){
    #pragma unroll
    for (int gg = 0; gg < 4; ++gg)
      #pragma unroll
      for (int r = 0; r < 4; ++r) accL0[gg][r] = e0r[gg][r];
    accK512_lds(accL0, h0A + hoff, smem, lane8);            // Whh0d * h0_287
  }
  #pragma unroll 1
  for (int t = 0; t < 288; ++t){
    if (isL0){
      // phase A: finish h0_t
      if (t > 0)
        accK512_lds(accL0, h1A + hoff, smem + 32768, lane8); // Wy * h1_{t-1}
      float s[4];
      #pragma unroll
      for (int r = 0; r < 4; ++r) s[r] = (t == 0) ? y0v[bq + r] : projB_val;
      float xv[4][6];
      #pragma unroll
      for (int r = 0; r < 4; ++r){
        const float* xr = xf + ((size_t)(bq + r)*288 + t)*6;
        #pragma unroll
        for (int kk = 0; kk < 6; ++kk) xv[r][kk] = xr[kk];
      }
      #pragma unroll
      for (int gg = 0; gg < 4; ++gg){
        #pragma unroll
        for (int r = 0; r < 4; ++r) accL0[gg][r] += wc[gg] * s[r];
        #pragma unroll
        for (int kk = 0; kk < 6; ++kk){
          float w = xw[gg][kk];
          #pragma unroll
          for (int r = 0; r < 4; ++r) accL0[gg][r] += w * xv[r][kk];
        }
      }
      pointwise(accL0, creg, bq, u, col, h0B);
    } else {
      // phase A: start accL1; emit y_{t-1}
      #pragma unroll
      for (int gg = 0; gg < 4; ++gg)
        #pragma unroll
        for (int r = 0; r < 4; ++r) accL1[gg][r] = b1r[gg];
      accK512_lds(accL1, h1A + hoff, smem + 32768, lane8);  // Whh1d * h1_{t-1}
      if (k < 36 && t > 0) emitY(h1A, t - 1);
    }
    if (groupbar(cntg, sub, ++gen, summary, go, abortf, &s_abort)) return;
    if (isL0){
      // phase B: prefetch accL0 for step t+1 (h0_t just published)
      if (t < 287){
        #pragma unroll
        for (int gg = 0; gg < 4; ++gg)
          #pragma unroll
          for (int r = 0; r < 4; ++r) accL0[gg][r] = e0r[gg][r];
        accK512_lds(accL0, h0B + hoff, smem, lane8);        // Whh0d * h0_t
      }
    } else {
      // phase B: finish h1_t
      accK512_lds(accL1, h0B + hoff, smem, lane8);          // Wih1d * h0_t
      pointwise(accL1, creg, bq, u, col, h1B);
    }
    if (groupbar(cntg, sub, ++gen, summary, go, abortf, &s_abort)) return;
    { uint16_t* t_ = h0A; h0A = h0B; h0B = t_; }
    { uint16_t* t_ = h1A; h1A = h1B; h1B = t_; }
  }

  // final y_287 (h1A = h1_287, published by last barrier)
  if (!isL0 && k < 36) emitY(h1A, 287);
}

// ---------------- prep: frag-ordered bf16 weights (+Wy), emb+bias folds ----
#define PREP_S 1048576
#define PREP_TOTAL (7*PREP_S + 1048576 + 6144)

__global__ void __launch_bounds__(256)
prep_kernel(const float* __restrict__ encWih0, const float* __restrict__ encWhh0,
            const float* __restrict__ encWih1, const float* __restrict__ encWhh1,
            const float* __restrict__ decWih0, const float* __restrict__ decWhh0,
            const float* __restrict__ decWih1, const float* __restrict__ decWhh1,
            const float* __restrict__ encbih0, const float* __restrict__ encbhh0,
            const float* __restrict__ encbih1, const float* __restrict__ encbhh1,
            const float* __restrict__ decbih0, const float* __restrict__ decbhh0,
            const float* __restrict__ decbih1, const float* __restrict__ decbhh1,
            const float* __restrict__ projW, const float* __restrict__ emb,
            const int* __restrict__ turb,
            uint16_t* Whh0e, uint16_t* Wih1e, uint16_t* Whh1e,
            uint16_t* Whh0d, uint16_t* Wih1d, uint16_t* Whh1d, uint16_t* Wyp,
            float* E0e, float* E0d, float* b1e, float* b1d, float* wcol0)
{
  int i = blockIdx.x*256 + threadIdx.x;
  if (i >= PREP_TOTAL) return;
  if (i < 7*PREP_S){
    // fragment reorder: dest = role*32768 + gate*8192 + kc*512 + lane*8 + j
    // value = W[gate*512 + role*16 + (lane&15)][kc*32 + (lane>>4)*8 + j]
    int w = i >> 20, r = i & (PREP_S - 1);
    int role = r >> 15;
    int rem  = r & 32767;
    int gate = rem >> 13;
    int kc   = (rem >> 9) & 15;
    int ln   = (rem >> 3) & 63;
    int j    = rem & 7;
    int c = ln & 15, q = ln >> 4;
    int row  = (gate << 9) + (role << 4) + c;
    int colk = (kc << 5) + (q << 3) + j;
    float v;
    if (w == 6){
      v = decWih0[(size_t)row*23] * projW[colk];     // Wy = wcol0 (x) projW
    } else {
      const float* src = (w==0)?encWhh0:(w==1)?encWih1:(w==2)?encWhh1:
                         (w==3)?decWhh0:(w==4)?decWih1:decWhh1;
      v = src[(size_t)row*512 + colk];
    }
    uint16_t* dst = (w==0)?Whh0e:(w==1)?Wih1e:(w==2)?Whh1e:
                    (w==3)?Whh0d:(w==4)?Wih1d:(w==5)?Whh1d:Wyp;
    dst[r] = f2bf(v);
  } else if (i < 7*PREP_S + 524288){
    int r = i - 7*PREP_S; int b = r >> 11, j = r & 2047;
    float s = encbih0[j] + encbhh0[j];
    const float* e = emb + (size_t)turb[b]*16;
    const float* wr = encWih0 + (size_t)j*24 + 8;
    #pragma unroll
    for (int m = 0; m < 16; ++m) s += e[m]*wr[m];
    E0e[r] = s;
  } else if (i < 7*PREP_S + 1048576){
    int r = i - 7*PREP_S - 524288; int b = r >> 11, j = r & 2047;
    float s = decbih0[j] + decbhh0[j];
    const float* e = emb + (size_t)turb[b]*16;
    const float* wr = decWih0 + (size_t)j*23 + 7;
    #pragma unroll
    for (int m = 0; m < 16; ++m) s += e[m]*wr[m];
    E0d[r] = s;
  } else {
    int r = i - 7*PREP_S - 1048576;
    if (r < 2048)      b1e[r] = encbih1[r] + encbhh1[r];
    else if (r < 4096){ int j = r - 2048; b1d[j] = decbih1[j] + decbhh1[j]; }
    else              { int j = r - 4096; wcol0[j] = decWih0[(size_t)j*23]; }
  }
}

// ---------------------------------------------------------------------------
extern "C" void kernel_launch(void* const* d_in, const int* in_sizes, int n_in,
                              void* d_out, int out_size, void* d_ws, size_t ws_size,
                              hipStream_t stream)
{
  const float* xh      = (const float*)d_in[0];
  const float* xf      = (const float*)d_in[1];
  const float* y0v     = (const float*)d_in[2];
  const int*   turb    = (const int*)d_in[3];
  const float* emb     = (const float*)d_in[5];
  const float* encWih0 = (const float*)d_in[6];
  const float* encWhh0 = (const float*)d_in[7];
  const float* encbih0 = (const float*)d_in[8];
  const float* encbhh0 = (const float*)d_in[9];
  const float* encWih1 = (const float*)d_in[10];
  const float* encWhh1 = (const float*)d_in[11];
  const float* encbih1 = (const float*)d_in[12];
  const float* encbhh1 = (const float*)d_in[13];
  const float* decWih0 = (const float*)d_in[14];
  const float* decWhh0 = (const float*)d_in[15];
  const float* decbih0 = (const float*)d_in[16];
  const float* decbhh0 = (const float*)d_in[17];
  const float* decWih1 = (const float*)d_in[18];
  const float* decWhh1 = (const float*)d_in[19];
  const float* decbih1 = (const float*)d_in[20];
  const float* decbhh1 = (const float*)d_in[21];
  const float* projW   = (const float*)d_in[22];
  const float* projB   = (const float*)d_in[23];
  float* out = (float*)d_out;

  char* ws = (char*)d_ws;
  constexpr size_t SZW = (size_t)2048*512*2;        // 2 MiB per matrix
  constexpr size_t OFF_Whh0e = 0;
  constexpr size_t OFF_Wih1e = SZW;
  constexpr size_t OFF_Whh1e = 2*SZW;
  constexpr size_t OFF_Whh0d = 3*SZW;
  constexpr size_t OFF_Wih1d = 4*SZW;
  constexpr size_t OFF_Whh1d = 5*SZW;
  constexpr size_t OFF_Wy    = 6*SZW;
  constexpr size_t OFF_E0e   = 7*SZW;
  constexpr size_t OFF_E0d   = OFF_E0e + 2097152;
  constexpr size_t OFF_b1e   = OFF_E0d + 2097152;
  constexpr size_t OFF_b1d   = OFF_b1e + 8192;
  constexpr size_t OFF_wcol0 = OFF_b1d + 8192;
  constexpr size_t OFF_h0    = OFF_wcol0 + 8192;
  constexpr size_t OFF_h1    = OFF_h0 + 524288;
  constexpr size_t OFF_cnt   = OFF_h1 + 524288;
  constexpr size_t ZERO_BYTES = 2*524288 + 4096;    // h0,h1 ping-pong + counter arena

  uint16_t* Whh0e = (uint16_t*)(ws + OFF_Whh0e);
  uint16_t* Wih1e = (uint16_t*)(ws + OFF_Wih1e);
  uint16_t* Whh1e = (uint16_t*)(ws + OFF_Whh1e);
  uint16_t* Whh0d = (uint16_t*)(ws + OFF_Whh0d);
  uint16_t* Wih1d = (uint16_t*)(ws + OFF_Wih1d);
  uint16_t* Whh1d = (uint16_t*)(ws + OFF_Whh1d);
  uint16_t* Wyp   = (uint16_t*)(ws + OFF_Wy);
  float* E0e   = (float*)(ws + OFF_E0e);
  float* E0d   = (float*)(ws + OFF_E0d);
  float* b1e   = (float*)(ws + OFF_b1e);
  float* b1d   = (float*)(ws + OFF_b1d);
  float* wcol0 = (float*)(ws + OFF_wcol0);
  uint16_t* h0p = (uint16_t*)(ws + OFF_h0);
  uint16_t* h1p = (uint16_t*)(ws + OFF_h1);
  unsigned* cntp = (unsigned*)(ws + OFF_cnt);

  hipMemsetAsync(ws + OFF_h0, 0, ZERO_BYTES, stream);

  prep_kernel<<<dim3((PREP_TOTAL + 255)/256), dim3(256), 0, stream>>>(
      encWih0, encWhh0, encWih1, encWhh1, decWih0, decWhh0, decWih1, decWhh1,
      encbih0, encbhh0, encbih1, encbhh1, decbih0, decbhh0, decbih1, decbhh1,
      projW, emb, turb,
      Whh0e, Wih1e, Whh1e, Whh0d, Wih1d, Whh1d, Wyp,
      E0e, E0d, b1e, b1d, wcol0);

  // Plain launch: 256 blocks x 256 thr x 128KiB LDS -> 1 block/CU, full GPU
  // (proven R24). Abort-guarded spins keep any failure container-safe.
  seq2seq_main<<<dim3(NBLK), dim3(NTHR), 0, stream>>>(
      Whh0e, Wih1e, Whh1e, Whh0d, Wih1d, Whh1d, Wyp,
      E0e, E0d, b1e, b1d, wcol0,
      h0p, h1p, xh, xf, y0v,
      encWih0, decWih0, projW, projB,
      out, cntp);
}